// Round 4
// baseline (1896.168 us; speedup 1.0000x reference)
//
#include <hip/hip_runtime.h>

typedef _Float16 half_t;
typedef _Float16 half8 __attribute__((ext_vector_type(8)));
typedef float f32x4 __attribute__((ext_vector_type(4)));
typedef float f32x2 __attribute__((ext_vector_type(2)));

#define B_TOT    262144
#define PRED_LEN 12
#define NBLK     (B_TOT/64)

// half-element offsets inside d_ws (R1-proven layout)
#define OFF_WHH 0            // 24ct * 4chunk * 64lane * 8 = 49152
#define OFF_WC  49152        // 24ct * 64lane * 8          = 12288 (K32 input frags w/ bias row)
#define OFF_W1S 61440        // 4*4*512                     = 8192
#define OFF_W1H 69632        // 4*4*512                     = 8192
#define OFF_W2  77824        // 2*512                       = 1024
#define HALFS_TOTAL 78848
#define NFLOATS 196          // b1[64], A_N*b_hh_n[128], b2[4]
#define PREP_TOTAL (HALFS_TOTAL + NFLOATS)

#define A_RZ (-1.44269504f)  // -log2(e): sigmoid(x)=rcp(1+exp2(acc))
#define A_N  (2.88539008f)   // 2*log2(e): tanh(y)=1-2*rcp(exp2(acc)+1)

#define K32(a,b,c) __builtin_amdgcn_mfma_f32_16x16x32_f16((a),(b),(c),0,0,0)

__device__ __forceinline__ float exp2f_(float x){ return __builtin_amdgcn_exp2f(x); }
__device__ __forceinline__ float rcpf_(float x){ return __builtin_amdgcn_rcpf(x); }

// ------------------------------------------------------------------
// prep: fold emb into W_ih, bake biases+log2 scales, emit fp16 frags
// (identical numerics to the R1-proven version)
// ------------------------------------------------------------------
__global__ void prep_kernel(const float* __restrict__ emb_W, const float* __restrict__ emb_b,
                            const float* __restrict__ W_ih, const float* __restrict__ W_hh,
                            const float* __restrict__ b_ih, const float* __restrict__ b_hh,
                            const float* __restrict__ W1,   const float* __restrict__ W2,
                            const float* __restrict__ b1,   const float* __restrict__ b2,
                            half_t* __restrict__ wsh, float* __restrict__ wsf) {
  int f = blockIdx.x*256 + threadIdx.x;
  if (f >= PREP_TOTAL) return;
  if (f < OFF_WC) {
    // W_hh K32 fragments: ct=g*8+jb, B[col][k], scale folded
    int e=f&7, l=(f>>3)&63, c=(f>>9)&3, ct=f>>11;
    int g=ct>>3, jb=ct&7;
    int col=g*128+jb*16+(l&15);
    int k=c*32+(l>>4)*8+e;
    float a=(g<2)?A_RZ:A_N;
    wsh[f]=(half_t)(a*W_hh[col*128+k]);
  } else if (f < OFF_W1S) {
    // folded input-GEMM K32 fragments: rows k0-7 = hi (*64), k8-15 = lo (/32 net),
    // k16 = bias (e==0), k17-31 = 0.  (R1-proven)
    int ff=f-OFF_WC;
    int e=ff&7, l=(ff>>3)&63, ct=ff>>9;
    int g=ct>>3, jb=ct&7;
    int col=g*128+jb*16+(l&15);
    int sub=l>>4;
    float a=(g<2)?A_RZ:A_N;
    float v=0.f;
    if (sub<=1) {
      float wc=0.f;
      for (int m=0;m<128;++m) wc = fmaf(W_ih[col*128+m], emb_W[m*8+e], wc);
      v = a*64.f*wc;
      if (sub==1) v *= (1.f/2048.f);
    } else if (sub==2 && e==0) {
      float bi=b_ih[col];
      for (int m=0;m<128;++m) bi = fmaf(W_ih[col*128+m], emb_b[m], bi);
      if (g<2) bi += b_hh[col];      // n-gate keeps b_hh separate (multiplied by r)
      v = a*bi;
    }
    wsh[f]=(half_t)v;
  } else if (f < OFF_W1H) {
    int ff=f-OFF_W1S;
    int e=ff&7, l=(ff>>3)&63, c=(ff>>9)&3, ct=ff>>11;
    int col=ct*16+(l&15);
    int k=c*32+(l>>4)*8+e;
    wsh[f]=(half_t)W1[col*256 + 128 + k];   // social half
  } else if (f < OFF_W2) {
    int ff=f-OFF_W1H;
    int e=ff&7, l=(ff>>3)&63, c=(ff>>9)&3, ct=ff>>11;
    int col=ct*16+(l&15);
    int k=c*32+(l>>4)*8+e;
    wsh[f]=(half_t)W1[col*256 + k];         // h half
  } else if (f < HALFS_TOTAL) {
    int ff=f-OFF_W2;
    int e=ff&7, l=(ff>>3)&63, c=ff>>9;
    int col=l&15;
    int k=c*32+(l>>4)*8+e;
    wsh[f]=(half_t)((col<4)?W2[col*64+k]:0.f);
  } else {
    int ff=f-HALFS_TOTAL;
    float v;
    if (ff < 64)       v = b1[ff];
    else if (ff < 192) v = A_N*b_hh[256 + (ff-64)];
    else               v = b2[ff-192];
    wsf[ff]=v;
  }
}

// hi/lo fp16 split, row stride 16: [0..7]=hi(*2^-6), [8..15]=lo(*2^11)
__device__ __forceinline__ void write_split(half_t* obsplit, int row, int s, float v){
  float scv = v * 0.015625f;
  half_t hi = (half_t)scv;
  float lo = (scv - (float)hi) * 2048.0f;
  obsplit[row*16 + s]     = hi;
  obsplit[row*16 + 8 + s] = (half_t)lo;
}

// stage [64][128] fp32 global tile into swizzled fp16 A-layout LDS tile
__device__ __forceinline__ void stage_tile(const float* __restrict__ src, half_t* htile,
                                           int b0, int tid){
  int row = tid>>3, cg = (tid&7)*16;
  const float* s = src + (size_t)(b0+row)*128 + cg;
  half8 p0, p1;
#pragma unroll
  for (int i=0;i<8;++i) p0[i] = (half_t)s[i];
#pragma unroll
  for (int i=0;i<8;++i) p1[i] = (half_t)s[8+i];
  int base = cg>>3;
  *(half8*)&htile[row*128 + (( base    ^ (row&15))<<3)] = p0;
  *(half8*)&htile[row*128 + (((base+1) ^ (row&15))<<3)] = p1;
}

// ------------------------------------------------------------------
// persistent decoder: 64 rows/block, 8 waves, wave owns 1 jb col-block
// 3 barriers/step, h double-buffered in LDS
// ------------------------------------------------------------------
__global__ __launch_bounds__(512, 4)
void decoder_kernel(const float* __restrict__ xy, const float* __restrict__ dxdy,
                    const float* __restrict__ social, const float* __restrict__ h0,
                    const half_t* __restrict__ wsh, const float* __restrict__ wsf,
                    float* __restrict__ out) {
  __shared__ half_t buf0[64*128], buf1[64*128];
  __shared__ half_t w1h_lds[8192];
  __shared__ half_t w2_lds[1024];
  __shared__ half_t z1t[64*64];
  __shared__ half_t obsplit[64*16];

  const int tid = threadIdx.x;
  const int wid = tid>>6, lane = tid&63;
  const int l15 = lane&15, l4 = lane>>4;
  const int b0 = blockIdx.x*64;

  // ---- resident weights: wave owns jb=wid (cols wid*16+l15), all 3 gates ----
  half8 Bg[3][4];
  half8 Bi[3];
#pragma unroll
  for (int g=0; g<3; ++g){
#pragma unroll
    for (int c=0;c<4;++c)
      Bg[g][c] = *(const half8*)(wsh + OFF_WHH + ((size_t)((g*8+wid)*4+c)*64 + lane)*8);
    Bi[g] = *(const half8*)(wsh + OFF_WC + ((size_t)(g*8+wid)*64 + lane)*8);
  }
  const int mycol = wid*16 + l15;
  const float bHN = wsf[64 + mycol];   // A_N * b_hh_n (kept out of MFMA: multiplied by r)

  // stage W1h + W2 fragments to LDS
  for (int i = tid; i < 1024; i += 512)
    *(half8*)&w1h_lds[i*8] = *(const half8*)(wsh + OFF_W1H + (size_t)i*8);
  if (tid < 128)
    *(half8*)&w2_lds[tid*8] = *(const half8*)(wsh + OFF_W2 + (size_t)tid*8);

  // ---- stage social into buf0, compute s_contrib (registers) ----
  stage_tile(social, buf0, b0, tid);
  __syncthreads();

  float sc[2][4];
  {
    int Mt = wid>>1;
    int arow = Mt*16 + l15;
    half8 ha[4];
#pragma unroll
    for (int c=0;c<4;++c){
      int slot = (c*4 + l4) ^ (arow&15);
      ha[c] = *(const half8*)&buf0[arow*128 + slot*8];
    }
#pragma unroll
    for (int c2=0;c2<2;++c2){
      int ct = (wid&1)*2 + c2;
      float b1v = wsf[ct*16 + l15];
      f32x4 acc = {b1v,b1v,b1v,b1v};
#pragma unroll
      for (int c=0;c<4;++c){
        half8 bw = *(const half8*)(wsh + OFF_W1S + ((size_t)(ct*4+c)*64 + lane)*8);
        acc = K32(ha[c], bw, acc);
      }
#pragma unroll
      for (int r=0;r<4;++r) sc[c2][r] = acc[r];
    }
  }
  __syncthreads();

  // ---- stage h0 into buf0, init obsplit ----
  stage_tile(h0, buf0, b0, tid);
  if (tid < 256) {
    int row = tid>>2, q = tid&3;
    size_t gb = (size_t)(b0+row)*4;
    if (q < 2) {
      write_split(obsplit, row, q,   xy[gb+q]);
      write_split(obsplit, row, q+2, xy[gb+q+2]);
    } else {
      int c0 = (q-2)*2;
      write_split(obsplit, row, 4+c0, dxdy[gb+c0]);
      write_split(obsplit, row, 5+c0, dxdy[gb+c0+1]);
    }
  }
  // ---- h_old master copy (fp32) for owned (row,col) elements ----
  float hq[4][4];
#pragma unroll
  for (int Mt=0;Mt<4;++Mt)
#pragma unroll
    for (int r=0;r<4;++r)
      hq[Mt][r] = h0[(size_t)(b0 + Mt*16 + l4*4 + r)*128 + mycol];

  // ---- fp32 obs masters for phase-C lanes (wid<4, l15<2): 4 rows each ----
  float obs_x[4], obs_w[4];
  if (wid < 4 && l15 < 2) {
#pragma unroll
    for (int r=0;r<4;++r){
      size_t gb = (size_t)(b0 + wid*16 + l4*4 + r)*4;
      obs_x[r] = xy[gb + l15];
      obs_w[r] = xy[gb + l15 + 2];
    }
  }
  __syncthreads();

  float* out0 = out;
  float* out1 = out + (size_t)PRED_LEN*B_TOT*4;

#pragma unroll 1
  for (int t=0; t<PRED_LEN; ++t) {
    const half_t* rb = (t&1) ? buf1 : buf0;
    half_t*       wb = (t&1) ? buf0 : buf1;

    // ---------- A1: gates + h update + publish to other buffer ----------
#pragma unroll
    for (int Mt=0; Mt<4; ++Mt) {
      int arow = Mt*16 + l15;
      half8 oa = {0,0,0,0,0,0,0,0};
      if (lane < 32)      oa = *(const half8*)&obsplit[arow*16 + l4*8];
      else if (lane < 48) oa[0] = (half_t)1.f;   // multiplies baked bias row (k=16)
      f32x4 ar  = {0.f,0.f,0.f,0.f};
      f32x4 az  = {0.f,0.f,0.f,0.f};
      f32x4 ain = {0.f,0.f,0.f,0.f};
      f32x4 ahn = {bHN,bHN,bHN,bHN};
      ar  = K32(oa, Bi[0], ar);
      az  = K32(oa, Bi[1], az);
      ain = K32(oa, Bi[2], ain);
      half8 ha0 = *(const half8*)&rb[arow*128 + (((0*4+l4)^(arow&15))<<3)];
      half8 ha1 = *(const half8*)&rb[arow*128 + (((1*4+l4)^(arow&15))<<3)];
      ar  = K32(ha0, Bg[0][0], ar);  az  = K32(ha0, Bg[1][0], az);  ahn = K32(ha0, Bg[2][0], ahn);
      ar  = K32(ha1, Bg[0][1], ar);  az  = K32(ha1, Bg[1][1], az);  ahn = K32(ha1, Bg[2][1], ahn);
      half8 ha2 = *(const half8*)&rb[arow*128 + (((2*4+l4)^(arow&15))<<3)];
      half8 ha3 = *(const half8*)&rb[arow*128 + (((3*4+l4)^(arow&15))<<3)];
      ar  = K32(ha2, Bg[0][2], ar);  az  = K32(ha2, Bg[1][2], az);  ahn = K32(ha2, Bg[2][2], ahn);
      ar  = K32(ha3, Bg[0][3], ar);  az  = K32(ha3, Bg[1][3], az);  ahn = K32(ha3, Bg[2][3], ahn);
#pragma unroll
      for (int r=0;r<4;++r){
        float R  = rcpf_(1.f + exp2f_(ar[r]));
        float Z  = rcpf_(1.f + exp2f_(az[r]));
        float np = fmaf(R, ahn[r], ain[r]);
        float N  = 1.f - 2.f*rcpf_(exp2f_(np) + 1.f);
        float h  = N + Z*(hq[Mt][r] - N);
        hq[Mt][r] = h;
        int hrow = Mt*16 + l4*4 + r;
        wb[hrow*128 + (((mycol>>3)^(hrow&15))<<3) + (mycol&7)] = (half_t)h;
      }
    }
    __syncthreads();

    // ---------- B: z1 = leaky(h_new @ W1h^T + s_contrib) ----------
    {
      int Mt = wid>>1;
      int arow = Mt*16 + l15;
      half8 ha[4];
#pragma unroll
      for (int c=0;c<4;++c){
        int slot = (c*4+l4) ^ (arow&15);
        ha[c] = *(const half8*)&wb[arow*128 + slot*8];
      }
#pragma unroll
      for (int c2=0;c2<2;++c2){
        int ct = (wid&1)*2 + c2;
        f32x4 acc = {sc[c2][0], sc[c2][1], sc[c2][2], sc[c2][3]};
#pragma unroll
        for (int c=0;c<4;++c){
          half8 bw = *(const half8*)&w1h_lds[((ct*4+c)*64 + lane)*8];
          acc = K32(ha[c], bw, acc);
        }
        int col = ct*16 + l15;
#pragma unroll
        for (int r=0;r<4;++r){
          int zrow = Mt*16 + l4*4 + r;
          float v = acc[r];
          v = fmaxf(v, 0.01f*v);
          z1t[zrow*64 + (((col>>3)^(zrow&7))<<3) + (col&7)] = (half_t)v;
        }
      }
    }
    __syncthreads();

    // ---------- C + transform (waves 0-3) ----------
    if (wid < 4) {
      int Mt = wid;
      int arow = Mt*16 + l15;
      half8 za0 = *(const half8*)&z1t[arow*64 + (((0*4+l4)^(arow&7))<<3)];
      half8 za1 = *(const half8*)&z1t[arow*64 + (((1*4+l4)^(arow&7))<<3)];
      half8 w2f0 = *(const half8*)&w2_lds[(0*64+lane)*8];
      half8 w2f1 = *(const half8*)&w2_lds[(1*64+lane)*8];
      float b2l = (l15<4) ? wsf[192+l15] : 0.f;
      f32x4 acc = {b2l,b2l,b2l,b2l};
      acc = K32(za0, w2f0, acc);
      acc = K32(za1, w2f1, acc);
      float d[4], dx1[4], dx2[4], dx3[4];
#pragma unroll
      for (int r=0;r<4;++r){
        float v = acc[r];
        d[r] = fmaxf(v, 0.01f*v);
      }
#pragma unroll
      for (int r=0;r<4;++r){
        dx1[r] = __shfl_xor(d[r], 1);
        dx2[r] = __shfl_xor(d[r], 2);
        dx3[r] = __shfl_xor(d[r], 3);
      }
      if (l15 < 4) {
        int q = l15;
#pragma unroll
        for (int r=0;r<4;++r){
          int row = Mt*16 + l4*4 + r;
          size_t ob = (size_t)((size_t)t*B_TOT + b0 + row)*4;
          if (q < 2) {
            float wh = obs_w[r] * exp2f_(dx2[r] * 1.44269504f);
            float xn = obs_x[r] + d[r] - 0.5f*wh;
            obs_x[r] = xn; obs_w[r] = wh;
            out0[ob + q]     = xn;
            out0[ob + q + 2] = wh;
            write_split(obsplit, row, q,   xn);
            write_split(obsplit, row, q+2, wh);
          } else if (q == 2) {
            f32x2 v = {dx2[r], dx3[r]};
            *(f32x2*)&out1[ob + 0] = v;
            write_split(obsplit, row, 4, dx2[r]);
            write_split(obsplit, row, 5, dx3[r]);
          } else {
            f32x2 v = {dx1[r], d[r]};
            *(f32x2*)&out1[ob + 2] = v;
            write_split(obsplit, row, 6, dx1[r]);
            write_split(obsplit, row, 7, d[r]);
          }
        }
      }
    }
    __syncthreads();
  }
}

extern "C" void kernel_launch(void* const* d_in, const int* in_sizes, int n_in,
                              void* d_out, int out_size, void* d_ws, size_t ws_size,
                              hipStream_t stream) {
  const float* xy     = (const float*)d_in[0];
  const float* dxdy   = (const float*)d_in[1];
  const float* social = (const float*)d_in[2];
  const float* h0     = (const float*)d_in[3];
  const float* emb_W  = (const float*)d_in[5];
  const float* emb_b  = (const float*)d_in[6];
  const float* W_ih   = (const float*)d_in[7];
  const float* W_hh   = (const float*)d_in[8];
  const float* b_ih   = (const float*)d_in[9];
  const float* b_hh   = (const float*)d_in[10];
  const float* W1     = (const float*)d_in[11];
  const float* b1     = (const float*)d_in[12];
  const float* W2     = (const float*)d_in[13];
  const float* b2     = (const float*)d_in[14];

  half_t* wsh = (half_t*)d_ws;
  float*  wsf = (float*)((char*)d_ws + (size_t)HALFS_TOTAL*2);

  prep_kernel<<<(PREP_TOTAL+255)/256, 256, 0, stream>>>(
      emb_W, emb_b, W_ih, W_hh, b_ih, b_hh, W1, W2, b1, b2, wsh, wsf);
  decoder_kernel<<<NBLK, 512, 0, stream>>>(
      xy, dxdy, social, h0, wsh, wsf, (float*)d_out);
}

// Round 5
// 840.994 us; speedup vs baseline: 2.2547x; 2.2547x over previous
//
#include <hip/hip_runtime.h>

typedef _Float16 half_t;
typedef _Float16 half8 __attribute__((ext_vector_type(8)));
typedef float f32x4 __attribute__((ext_vector_type(4)));
typedef float f32x2 __attribute__((ext_vector_type(2)));

#define B_TOT    262144
#define PRED_LEN 12
#define NBLK     (B_TOT/64)

// half-element offsets inside d_ws (R1-proven layout)
#define OFF_WHH 0            // 24ct * 4chunk * 64lane * 8 = 49152
#define OFF_WC  49152        // 24ct * 64lane * 8          = 12288 (K32 input frags w/ bias row)
#define OFF_W1S 61440        // 4*4*512                     = 8192
#define OFF_W1H 69632        // 4*4*512                     = 8192
#define OFF_W2  77824        // 2*512                       = 1024
#define HALFS_TOTAL 78848
#define NFLOATS 196          // b1[64], A_N*b_hh_n[128], b2[4]
#define PREP_TOTAL (HALFS_TOTAL + NFLOATS)

#define A_RZ (-1.44269504f)  // -log2(e): sigmoid(x)=rcp(1+exp2(acc))
#define A_N  (2.88539008f)   // 2*log2(e): tanh(y)=1-2*rcp(exp2(acc)+1)

#define K32(a,b,c) __builtin_amdgcn_mfma_f32_16x16x32_f16((a),(b),(c),0,0,0)

__device__ __forceinline__ float exp2f_(float x){ return __builtin_amdgcn_exp2f(x); }
__device__ __forceinline__ float rcpf_(float x){ return __builtin_amdgcn_rcpf(x); }

// ------------------------------------------------------------------
// prep: fold emb into W_ih, bake biases+log2 scales, emit fp16 frags
// (identical numerics to R1/R4)
// ------------------------------------------------------------------
__global__ void prep_kernel(const float* __restrict__ emb_W, const float* __restrict__ emb_b,
                            const float* __restrict__ W_ih, const float* __restrict__ W_hh,
                            const float* __restrict__ b_ih, const float* __restrict__ b_hh,
                            const float* __restrict__ W1,   const float* __restrict__ W2,
                            const float* __restrict__ b1,   const float* __restrict__ b2,
                            half_t* __restrict__ wsh, float* __restrict__ wsf) {
  int f = blockIdx.x*256 + threadIdx.x;
  if (f >= PREP_TOTAL) return;
  if (f < OFF_WC) {
    int e=f&7, l=(f>>3)&63, c=(f>>9)&3, ct=f>>11;
    int g=ct>>3, jb=ct&7;
    int col=g*128+jb*16+(l&15);
    int k=c*32+(l>>4)*8+e;
    float a=(g<2)?A_RZ:A_N;
    wsh[f]=(half_t)(a*W_hh[col*128+k]);
  } else if (f < OFF_W1S) {
    // folded input-GEMM K32 fragments: k0-7 hi (*64), k8-15 lo (/32 net),
    // k16 bias (e==0), rest 0
    int ff=f-OFF_WC;
    int e=ff&7, l=(ff>>3)&63, ct=ff>>9;
    int g=ct>>3, jb=ct&7;
    int col=g*128+jb*16+(l&15);
    int sub=l>>4;
    float a=(g<2)?A_RZ:A_N;
    float v=0.f;
    if (sub<=1) {
      float wc=0.f;
      for (int m=0;m<128;++m) wc = fmaf(W_ih[col*128+m], emb_W[m*8+e], wc);
      v = a*64.f*wc;
      if (sub==1) v *= (1.f/2048.f);
    } else if (sub==2 && e==0) {
      float bi=b_ih[col];
      for (int m=0;m<128;++m) bi = fmaf(W_ih[col*128+m], emb_b[m], bi);
      if (g<2) bi += b_hh[col];      // n-gate keeps b_hh separate (multiplied by r)
      v = a*bi;
    }
    wsh[f]=(half_t)v;
  } else if (f < OFF_W1H) {
    int ff=f-OFF_W1S;
    int e=ff&7, l=(ff>>3)&63, c=(ff>>9)&3, ct=ff>>11;
    int col=ct*16+(l&15);
    int k=c*32+(l>>4)*8+e;
    wsh[f]=(half_t)W1[col*256 + 128 + k];   // social half
  } else if (f < OFF_W2) {
    int ff=f-OFF_W1H;
    int e=ff&7, l=(ff>>3)&63, c=(ff>>9)&3, ct=ff>>11;
    int col=ct*16+(l&15);
    int k=c*32+(l>>4)*8+e;
    wsh[f]=(half_t)W1[col*256 + k];         // h half
  } else if (f < HALFS_TOTAL) {
    int ff=f-OFF_W2;
    int e=ff&7, l=(ff>>3)&63, c=ff>>9;
    int col=l&15;
    int k=c*32+(l>>4)*8+e;
    wsh[f]=(half_t)((col<4)?W2[col*64+k]:0.f);
  } else {
    int ff=f-HALFS_TOTAL;
    float v;
    if (ff < 64)       v = b1[ff];
    else if (ff < 192) v = A_N*b_hh[256 + (ff-64)];
    else               v = b2[ff-192];
    wsf[ff]=v;
  }
}

// hi/lo fp16 split, row stride 16: [0..7]=hi(*2^-6), [8..15]=lo(*2^11)
__device__ __forceinline__ void write_split(half_t* obsplit, int row, int s, float v){
  float scv = v * 0.015625f;
  half_t hi = (half_t)scv;
  float lo = (scv - (float)hi) * 2048.0f;
  obsplit[row*16 + s]     = hi;
  obsplit[row*16 + 8 + s] = (half_t)lo;
}

// stage [64][128] fp32 global tile into swizzled fp16 A-layout LDS tile
__device__ __forceinline__ void stage_tile(const float* __restrict__ src, half_t* htile,
                                           int b0, int tid){
  int row = tid>>3, cg = (tid&7)*16;
  const float* s = src + (size_t)(b0+row)*128 + cg;
  half8 p0, p1;
#pragma unroll
  for (int i=0;i<8;++i) p0[i] = (half_t)s[i];
#pragma unroll
  for (int i=0;i<8;++i) p1[i] = (half_t)s[8+i];
  int base = cg>>3;
  *(half8*)&htile[row*128 + (( base    ^ (row&15))<<3)] = p0;
  *(half8*)&htile[row*128 + (((base+1) ^ (row&15))<<3)] = p1;
}

// ------------------------------------------------------------------
// persistent decoder: 64 rows/block, 8 waves, wave owns 1 jb col-block
// 3 barriers/step, h double-buffered in LDS
// ------------------------------------------------------------------
__global__ __launch_bounds__(512, 2)
void decoder_kernel(const float* __restrict__ xy, const float* __restrict__ dxdy,
                    const float* __restrict__ social, const float* __restrict__ h0,
                    const half_t* __restrict__ wsh, const float* __restrict__ wsf,
                    float* __restrict__ out) {
  __shared__ half_t buf0[64*128], buf1[64*128];
  __shared__ half_t w1h_lds[8192];
  __shared__ half_t w2_lds[1024];
  __shared__ half_t z1t[64*64];
  __shared__ half_t obsplit[64*16];
  __shared__ float  obsf[64*4];        // fp32 obs masters (x,y,w,h), same-lane RW

  const int tid = threadIdx.x;
  const int wid = tid>>6, lane = tid&63;
  const int l15 = lane&15, l4 = lane>>4;
  const int b0 = blockIdx.x*64;

  // ---- resident weights: wave owns jb=wid (cols wid*16+l15), all 3 gates ----
  half8 Bg[3][4];
  half8 Bi[3];
#pragma unroll
  for (int g=0; g<3; ++g){
#pragma unroll
    for (int c=0;c<4;++c)
      Bg[g][c] = *(const half8*)(wsh + OFF_WHH + ((size_t)((g*8+wid)*4+c)*64 + lane)*8);
    Bi[g] = *(const half8*)(wsh + OFF_WC + ((size_t)(g*8+wid)*64 + lane)*8);
  }
  const int mycol = wid*16 + l15;
  const float bHN = wsf[64 + mycol];   // A_N * b_hh_n (kept out of MFMA: multiplied by r)

  // stage W1h + W2 fragments to LDS
  for (int i = tid; i < 1024; i += 512)
    *(half8*)&w1h_lds[i*8] = *(const half8*)(wsh + OFF_W1H + (size_t)i*8);
  if (tid < 128)
    *(half8*)&w2_lds[tid*8] = *(const half8*)(wsh + OFF_W2 + (size_t)tid*8);

  // ---- stage social into buf0, compute s_contrib (registers) ----
  stage_tile(social, buf0, b0, tid);
  __syncthreads();

  float sc[2][4];
  {
    int Mt = wid>>1;
    int arow = Mt*16 + l15;
    half8 ha[4];
#pragma unroll
    for (int c=0;c<4;++c){
      int slot = (c*4 + l4) ^ (arow&15);
      ha[c] = *(const half8*)&buf0[arow*128 + slot*8];
    }
#pragma unroll
    for (int c2=0;c2<2;++c2){
      int ct = (wid&1)*2 + c2;
      float b1v = wsf[ct*16 + l15];
      f32x4 acc = {b1v,b1v,b1v,b1v};
#pragma unroll
      for (int c=0;c<4;++c){
        half8 bw = *(const half8*)(wsh + OFF_W1S + ((size_t)(ct*4+c)*64 + lane)*8);
        acc = K32(ha[c], bw, acc);
      }
#pragma unroll
      for (int r=0;r<4;++r) sc[c2][r] = acc[r];
    }
  }
  __syncthreads();

  // ---- stage h0 into buf0, init obsplit + fp32 obs masters ----
  stage_tile(h0, buf0, b0, tid);
  if (tid < 256) {
    int row = tid>>2, q = tid&3;
    size_t gb = (size_t)(b0+row)*4;
    if (q < 2) {
      float vx = xy[gb+q], vw = xy[gb+q+2];
      write_split(obsplit, row, q,   vx);
      write_split(obsplit, row, q+2, vw);
      obsf[row*4 + q]     = vx;
      obsf[row*4 + q + 2] = vw;
    } else {
      int c0 = (q-2)*2;
      write_split(obsplit, row, 4+c0, dxdy[gb+c0]);
      write_split(obsplit, row, 5+c0, dxdy[gb+c0+1]);
    }
  }
  // ---- h_old master copy (fp32) for owned (row,col) elements ----
  float hq[4][4];
#pragma unroll
  for (int Mt=0;Mt<4;++Mt)
#pragma unroll
    for (int r=0;r<4;++r)
      hq[Mt][r] = h0[(size_t)(b0 + Mt*16 + l4*4 + r)*128 + mycol];
  __syncthreads();

  float* out0 = out;
  float* out1 = out + (size_t)PRED_LEN*B_TOT*4;

#pragma unroll 1
  for (int t=0; t<PRED_LEN; ++t) {
    const half_t* rb = (t&1) ? buf1 : buf0;
    half_t*       wb = (t&1) ? buf0 : buf1;

    // ---------- A1: gates + h update + publish to other buffer ----------
#pragma unroll
    for (int Mt=0; Mt<4; ++Mt) {
      int arow = Mt*16 + l15;
      half8 oa = {0,0,0,0,0,0,0,0};
      if (lane < 32)      oa = *(const half8*)&obsplit[arow*16 + l4*8];
      else if (lane < 48) oa[0] = (half_t)1.f;   // multiplies baked bias row (k=16)
      f32x4 ar  = {0.f,0.f,0.f,0.f};
      f32x4 az  = {0.f,0.f,0.f,0.f};
      f32x4 ain = {0.f,0.f,0.f,0.f};
      f32x4 ahn = {bHN,bHN,bHN,bHN};
      ar  = K32(oa, Bi[0], ar);
      az  = K32(oa, Bi[1], az);
      ain = K32(oa, Bi[2], ain);
      half8 ha0 = *(const half8*)&rb[arow*128 + (((0*4+l4)^(arow&15))<<3)];
      half8 ha1 = *(const half8*)&rb[arow*128 + (((1*4+l4)^(arow&15))<<3)];
      ar  = K32(ha0, Bg[0][0], ar);  az  = K32(ha0, Bg[1][0], az);  ahn = K32(ha0, Bg[2][0], ahn);
      ar  = K32(ha1, Bg[0][1], ar);  az  = K32(ha1, Bg[1][1], az);  ahn = K32(ha1, Bg[2][1], ahn);
      half8 ha2 = *(const half8*)&rb[arow*128 + (((2*4+l4)^(arow&15))<<3)];
      half8 ha3 = *(const half8*)&rb[arow*128 + (((3*4+l4)^(arow&15))<<3)];
      ar  = K32(ha2, Bg[0][2], ar);  az  = K32(ha2, Bg[1][2], az);  ahn = K32(ha2, Bg[2][2], ahn);
      ar  = K32(ha3, Bg[0][3], ar);  az  = K32(ha3, Bg[1][3], az);  ahn = K32(ha3, Bg[2][3], ahn);
#pragma unroll
      for (int r=0;r<4;++r){
        float R  = rcpf_(1.f + exp2f_(ar[r]));
        float Z  = rcpf_(1.f + exp2f_(az[r]));
        float np = fmaf(R, ahn[r], ain[r]);
        float N  = 1.f - 2.f*rcpf_(exp2f_(np) + 1.f);
        float h  = N + Z*(hq[Mt][r] - N);
        hq[Mt][r] = h;
        int hrow = Mt*16 + l4*4 + r;
        wb[hrow*128 + (((mycol>>3)^(hrow&15))<<3) + (mycol&7)] = (half_t)h;
      }
    }
    __syncthreads();

    // ---------- B: z1 = leaky(h_new @ W1h^T + s_contrib) ----------
    {
      int Mt = wid>>1;
      int arow = Mt*16 + l15;
      half8 ha[4];
#pragma unroll
      for (int c=0;c<4;++c){
        int slot = (c*4+l4) ^ (arow&15);
        ha[c] = *(const half8*)&wb[arow*128 + slot*8];
      }
#pragma unroll
      for (int c2=0;c2<2;++c2){
        int ct = (wid&1)*2 + c2;
        f32x4 acc = {sc[c2][0], sc[c2][1], sc[c2][2], sc[c2][3]};
#pragma unroll
        for (int c=0;c<4;++c){
          half8 bw = *(const half8*)&w1h_lds[((ct*4+c)*64 + lane)*8];
          acc = K32(ha[c], bw, acc);
        }
        int col = ct*16 + l15;
#pragma unroll
        for (int r=0;r<4;++r){
          int zrow = Mt*16 + l4*4 + r;
          float v = acc[r];
          v = fmaxf(v, 0.01f*v);
          z1t[zrow*64 + (((col>>3)^(zrow&7))<<3) + (col&7)] = (half_t)v;
        }
      }
    }
    __syncthreads();

    // ---------- C + transform (waves 0-3) ----------
    if (wid < 4) {
      int Mt = wid;
      int arow = Mt*16 + l15;
      half8 za0 = *(const half8*)&z1t[arow*64 + (((0*4+l4)^(arow&7))<<3)];
      half8 za1 = *(const half8*)&z1t[arow*64 + (((1*4+l4)^(arow&7))<<3)];
      half8 w2f0 = *(const half8*)&w2_lds[(0*64+lane)*8];
      half8 w2f1 = *(const half8*)&w2_lds[(1*64+lane)*8];
      float b2l = (l15<4) ? wsf[192+l15] : 0.f;
      f32x4 acc = {b2l,b2l,b2l,b2l};
      acc = K32(za0, w2f0, acc);
      acc = K32(za1, w2f1, acc);
      float d[4], dx1[4], dx2[4], dx3[4];
#pragma unroll
      for (int r=0;r<4;++r){
        float v = acc[r];
        d[r] = fmaxf(v, 0.01f*v);
      }
#pragma unroll
      for (int r=0;r<4;++r){
        dx1[r] = __shfl_xor(d[r], 1);
        dx2[r] = __shfl_xor(d[r], 2);
        dx3[r] = __shfl_xor(d[r], 3);
      }
      if (l15 < 4) {
        int q = l15;
#pragma unroll
        for (int r=0;r<4;++r){
          int row = Mt*16 + l4*4 + r;
          size_t ob = (size_t)((size_t)t*B_TOT + b0 + row)*4;
          if (q < 2) {
            float x = obsf[row*4 + q];
            float w = obsf[row*4 + q + 2];
            float wh = w * exp2f_(dx2[r] * 1.44269504f);
            float xn = x + d[r] - 0.5f*wh;
            obsf[row*4 + q]     = xn;
            obsf[row*4 + q + 2] = wh;
            out0[ob + q]     = xn;
            out0[ob + q + 2] = wh;
            write_split(obsplit, row, q,   xn);
            write_split(obsplit, row, q+2, wh);
          } else if (q == 2) {
            f32x2 v = {dx2[r], dx3[r]};
            *(f32x2*)&out1[ob + 0] = v;
            write_split(obsplit, row, 4, dx2[r]);
            write_split(obsplit, row, 5, dx3[r]);
          } else {
            f32x2 v = {dx1[r], d[r]};
            *(f32x2*)&out1[ob + 2] = v;
            write_split(obsplit, row, 6, dx1[r]);
            write_split(obsplit, row, 7, d[r]);
          }
        }
      }
    }
    __syncthreads();
  }
}

extern "C" void kernel_launch(void* const* d_in, const int* in_sizes, int n_in,
                              void* d_out, int out_size, void* d_ws, size_t ws_size,
                              hipStream_t stream) {
  const float* xy     = (const float*)d_in[0];
  const float* dxdy   = (const float*)d_in[1];
  const float* social = (const float*)d_in[2];
  const float* h0     = (const float*)d_in[3];
  const float* emb_W  = (const float*)d_in[5];
  const float* emb_b  = (const float*)d_in[6];
  const float* W_ih   = (const float*)d_in[7];
  const float* W_hh   = (const float*)d_in[8];
  const float* b_ih   = (const float*)d_in[9];
  const float* b_hh   = (const float*)d_in[10];
  const float* W1     = (const float*)d_in[11];
  const float* b1     = (const float*)d_in[12];
  const float* W2     = (const float*)d_in[13];
  const float* b2     = (const float*)d_in[14];

  half_t* wsh = (half_t*)d_ws;
  float*  wsf = (float*)((char*)d_ws + (size_t)HALFS_TOTAL*2);

  prep_kernel<<<(PREP_TOTAL+255)/256, 256, 0, stream>>>(
      emb_W, emb_b, W_ih, W_hh, b_ih, b_hh, W1, W2, b1, b2, wsh, wsf);
  decoder_kernel<<<NBLK, 512, 0, stream>>>(
      xy, dxdy, social, h0, wsh, wsf, (float*)d_out);
}